// Round 4
// baseline (1098.842 us; speedup 1.0000x reference)
//
#include <hip/hip_runtime.h>
#include <math.h>

#define G 20000
#define E_EDGES 640000
#define HID 64
#define NHEAD 4
#define BATCH 128
#define PD 600
#define NEG 0.2f
#define MAXE 1024
#define KSPLIT 33
#define KCH 608    // 33*608 = 20064, 608 % 8 == 0

__device__ __forceinline__ float sigmoidf_(float x){ return 1.0f/(1.0f+__expf(-x)); }
__device__ __forceinline__ float leakyf_(float x){ return x>=0.f ? x : NEG*x; }

// ---------- Stage 1: hc = [x | gene_embed[pos]] @ [conv1_W | lin1_W]  (G x 320) ----------
__global__ void k_hc(const float* __restrict__ x, const int* __restrict__ pos,
                     const float* __restrict__ ge, const float* __restrict__ Wc,
                     const float* __restrict__ Wl, float* __restrict__ hc)
{
    int i = blockIdx.x;
    int t = threadIdx.x; // 320 threads
    __shared__ float xc[65];
    if (t < 65) xc[t] = (t == 0) ? x[i] : ge[pos[i]*HID + (t-1)];
    __syncthreads();
    float acc = 0.f;
    if (t < 256) {
        for (int k = 0; k < 65; ++k) acc += xc[k] * Wc[k*256 + t];
    } else {
        int c = t - 256;
        for (int k = 0; k < 65; ++k) acc += xc[k] * Wl[k*64 + c];
    }
    hc[i*320 + t] = acc;
}

// ---------- e_src / e_dst for conv1 ----------
__global__ void k_attn_coef(const float* __restrict__ hc, const float* __restrict__ as_,
                            const float* __restrict__ ad_, float* __restrict__ es,
                            float* __restrict__ ed)
{
    int i = blockIdx.x; int t = threadIdx.x; // 256
    float hv = hc[i*320 + t];
    float v1 = hv * as_[t];
    float v2 = hv * ad_[t];
    for (int m = 32; m; m >>= 1) { v1 += __shfl_xor(v1, m); v2 += __shfl_xor(v2, m); }
    if ((t & 63) == 0) { int h = t >> 6; es[i*4+h] = v1; ed[i*4+h] = v2; }
}

// ---------- CSR build ----------
__global__ void k_hist(const int* __restrict__ ei, int* __restrict__ cnt){
    int e = blockIdx.x*blockDim.x + threadIdx.x;
    if (e < E_EDGES) atomicAdd(&cnt[ei[E_EDGES + e]], 1);
}
__global__ void k_scan(const int* __restrict__ cnt, int* __restrict__ offs){
    __shared__ int buf[1024];
    __shared__ int carry;
    int t = threadIdx.x;
    if (t == 0){ carry = 0; offs[0] = 0; }
    __syncthreads();
    for (int base = 0; base < G; base += 1024){
        int v = (base + t < G) ? cnt[base + t] : 0;
        buf[t] = v; __syncthreads();
        for (int off = 1; off < 1024; off <<= 1){
            int add = (t >= off) ? buf[t - off] : 0;
            __syncthreads();
            buf[t] += add;
            __syncthreads();
        }
        if (base + t < G) offs[base + t + 1] = carry + buf[t];
        __syncthreads();
        if (t == 0) carry += buf[1023];
        __syncthreads();
    }
}
__global__ void k_cursor(const int* __restrict__ offs, int* __restrict__ cur){
    int i = blockIdx.x*blockDim.x + threadIdx.x;
    if (i < G) cur[i] = offs[i];
}
__global__ void k_scatter(const int* __restrict__ ei, int* __restrict__ cur, int* __restrict__ csr){
    int e = blockIdx.x*blockDim.x + threadIdx.x;
    if (e < E_EDGES){
        int d = ei[E_EDGES + e];
        int p = atomicAdd(&cur[d], 1);
        csr[p] = ei[e];
    }
}

// ---------- GAT1 apply ----------
__global__ void k_gat1(const float* __restrict__ hc, const float* __restrict__ es,
                       const float* __restrict__ ed, const int* __restrict__ offs,
                       const int* __restrict__ csr, const float* __restrict__ bc1,
                       const float* __restrict__ bl1, float* __restrict__ h1)
{
    int d = blockIdx.x; int t = threadIdx.x; // 256
    __shared__ float cache[MAXE*4];
    __shared__ int   ssrc[MAXE];
    __shared__ float red[256];
    __shared__ float bc[8];
    int o = offs[d];
    int deg = offs[d+1] - o;
    int total = deg + 1;              // + self loop
    if (total > MAXE) total = MAXE;
    float edst[4];
    #pragma unroll
    for (int h = 0; h < 4; ++h) edst[h] = ed[d*4+h];
    float lmax[4] = {-1e30f,-1e30f,-1e30f,-1e30f};
    for (int idx = t; idx < total; idx += 256){
        int s = (idx < deg) ? csr[o + idx] : d;
        ssrc[idx] = s;
        #pragma unroll
        for (int h = 0; h < 4; ++h){
            float e = leakyf_(es[s*4+h] + edst[h]);
            cache[idx*4+h] = e;
            lmax[h] = fmaxf(lmax[h], e);
        }
    }
    __syncthreads();
    #pragma unroll
    for (int h = 0; h < 4; ++h){
        red[t] = lmax[h]; __syncthreads();
        for (int s2 = 128; s2; s2 >>= 1){ if (t < s2) red[t] = fmaxf(red[t], red[t+s2]); __syncthreads(); }
        if (t == 0) bc[h] = red[0];
        __syncthreads();
    }
    float m0 = bc[0], m1 = bc[1], m2 = bc[2], m3 = bc[3];
    float lsum[4] = {0.f,0.f,0.f,0.f};
    for (int idx = t; idx < total; idx += 256){
        float e0 = __expf(cache[idx*4+0] - m0); cache[idx*4+0] = e0; lsum[0] += e0;
        float e1 = __expf(cache[idx*4+1] - m1); cache[idx*4+1] = e1; lsum[1] += e1;
        float e2 = __expf(cache[idx*4+2] - m2); cache[idx*4+2] = e2; lsum[2] += e2;
        float e3 = __expf(cache[idx*4+3] - m3); cache[idx*4+3] = e3; lsum[3] += e3;
    }
    __syncthreads();
    #pragma unroll
    for (int h = 0; h < 4; ++h){
        red[t] = lsum[h]; __syncthreads();
        for (int s2 = 128; s2; s2 >>= 1){ if (t < s2) red[t] += red[t+s2]; __syncthreads(); }
        if (t == 0) bc[4+h] = 1.0f / red[0];
        __syncthreads();
    }
    int h = t >> 6, c = t & 63;
    float inv = bc[4+h];
    float acc = 0.f;
    for (int idx = 0; idx < total; ++idx){
        int s = ssrc[idx];
        float alpha = cache[idx*4+h] * inv;
        acc += alpha * hc[s*320 + h*64 + c];
    }
    red[t] = acc;
    __syncthreads();
    if (t < 64){
        float sum = red[t] + red[64+t] + red[128+t] + red[192+t];
        float val = 0.25f*sum + bc1[t] + hc[d*320 + 256 + t] + bl1[t];
        h1[d*64 + t] = sigmoidf_(val);
    }
}

// ---------- conv2 prep ----------
__global__ void k_conv2prep(const float* __restrict__ h1, const float* __restrict__ W2c,
                            const float* __restrict__ as2, const float* __restrict__ ad2,
                            const float* __restrict__ Wl2, float* __restrict__ hh2,
                            float* __restrict__ es2, float* __restrict__ ed2,
                            float* __restrict__ lv)
{
    int i = blockIdx.x; int k = threadIdx.x; // 64
    float hv = h1[i*64 + k];
    #pragma unroll
    for (int j = 0; j < 4; ++j){
        float v = hv * W2c[k*4 + j];
        for (int m = 32; m; m >>= 1) v += __shfl_xor(v, m);
        if (k == 0){ hh2[i*4+j] = v; es2[i*4+j] = v*as2[j]; ed2[i*4+j] = v*ad2[j]; }
    }
    float v = hv * Wl2[k];
    for (int m = 32; m; m >>= 1) v += __shfl_xor(v, m);
    if (k == 0) lv[i] = v;
}

// ---------- GAT2 apply ----------
__global__ void k_gat2(const float* __restrict__ hh2, const float* __restrict__ es2,
                       const float* __restrict__ ed2, const int* __restrict__ offs,
                       const int* __restrict__ csr, const float* __restrict__ lv,
                       const float* __restrict__ bc2, const float* __restrict__ bl2,
                       float* __restrict__ feat)
{
    int d = blockIdx.x; int j = threadIdx.x; // 64
    int o = offs[d];
    int deg = offs[d+1] - o;
    int total = deg + 1;
    float edst[4];
    #pragma unroll
    for (int h = 0; h < 4; ++h) edst[h] = ed2[d*4+h];
    float lmax[4] = {-1e30f,-1e30f,-1e30f,-1e30f};
    for (int idx = j; idx < total; idx += 64){
        int s = (idx < deg) ? csr[o + idx] : d;
        #pragma unroll
        for (int h = 0; h < 4; ++h)
            lmax[h] = fmaxf(lmax[h], leakyf_(es2[s*4+h] + edst[h]));
    }
    #pragma unroll
    for (int h = 0; h < 4; ++h)
        for (int m = 32; m; m >>= 1) lmax[h] = fmaxf(lmax[h], __shfl_xor(lmax[h], m));
    float lsum[4] = {0.f,0.f,0.f,0.f};
    float lnum[4] = {0.f,0.f,0.f,0.f};
    for (int idx = j; idx < total; idx += 64){
        int s = (idx < deg) ? csr[o + idx] : d;
        #pragma unroll
        for (int h = 0; h < 4; ++h){
            float e  = leakyf_(es2[s*4+h] + edst[h]);
            float ex = __expf(e - lmax[h]);
            lsum[h] += ex;
            lnum[h] += ex * hh2[s*4+h];
        }
    }
    #pragma unroll
    for (int h = 0; h < 4; ++h){
        for (int m = 32; m; m >>= 1){ lsum[h] += __shfl_xor(lsum[h], m); lnum[h] += __shfl_xor(lnum[h], m); }
    }
    if (j == 0){
        float sum = 0.f;
        #pragma unroll
        for (int h = 0; h < 4; ++h) sum += lnum[h] / lsum[h];
        feat[d] = sigmoidf_(0.25f*sum + bc2[0] + lv[d] + bl2[0]);
    }
}

// ---------- transpose: inpT[k][row] = ctrl[row][k] + feat[k]  (k < 20000) ----------
__global__ void k_transpose(const float* __restrict__ ctrl, const float* __restrict__ feat,
                            float* __restrict__ inpT)
{
    __shared__ float tile[64][65];
    int kb = blockIdx.x, rb = blockIdx.y;
    int tx = threadIdx.x & 63, ty4 = threadIdx.x >> 6;
    int k = kb*64 + tx;
    #pragma unroll
    for (int rr = ty4; rr < 64; rr += 4){
        int row = rb*64 + rr;
        tile[rr][tx] = (k < 20000) ? ctrl[(size_t)row*20000 + k] : 0.f;
    }
    __syncthreads();
    #pragma unroll
    for (int kk = ty4; kk < 64; kk += 4){
        int kg = kb*64 + kk;
        if (kg < 20000)
            inpT[(size_t)kg*128 + rb*64 + tx] = tile[tx][kk] + feat[kg];
    }
}

// ---------- pert MLP -> writes inpT rows 20000..20063 directly ----------
__global__ void k_pert(const float* __restrict__ pert, const float* __restrict__ W1,
                       const float* __restrict__ b1, const float* __restrict__ W2,
                       const float* __restrict__ b2, float* __restrict__ inpT)
{
    int r = blockIdx.x; int t = threadIdx.x; // 128
    __shared__ float hid[128];
    float acc = 0.f;
    for (int k = 0; k < PD; ++k) acc += pert[r*PD + k] * W1[k*128 + t];
    hid[t] = sigmoidf_(acc + b1[t]);
    __syncthreads();
    if (t < 64){
        float a2 = 0.f;
        for (int k = 0; k < 128; ++k) a2 += hid[k] * W2[k*64 + t];
        inpT[(size_t)(20000 + t)*128 + r] = a2 + b2[t];
    }
}

// ---------- pred GEMM1: 128x64 tile, A+B staged in LDS, double-buffered ----------
// grid (16, KSPLIT); thread = 8 rows x 4 cols
__global__ __launch_bounds__(256, 4)
void k_gemm1(const float* __restrict__ inpT, const float* __restrict__ W1,
             float* __restrict__ part)
{
    int t = threadIdx.x;
    int colbase = blockIdx.x * 64;
    int ks = blockIdx.y;
    int kbeg = ks * KCH;
    __shared__ float As[2][8][128];
    __shared__ float Bs[2][8][64];
    float acc[8][4];
    #pragma unroll
    for (int i = 0; i < 8; ++i)
        #pragma unroll
        for (int j = 0; j < 4; ++j) acc[i][j] = 0.f;

    int sakk = t >> 5, sarow = (t & 31) * 4;   // A staging: all 256 threads
    int sbkk = t >> 4, sbcol = (t & 15) * 4;   // B staging: t < 128
    bool bload = t < 128;

    *(float4*)&As[0][sakk][sarow] =
        *(const float4*)(inpT + (size_t)(kbeg + sakk)*128 + sarow);
    if (bload)
        *(float4*)&Bs[0][sbkk][sbcol] =
            *(const float4*)(W1 + (size_t)(kbeg + sbkk)*1024 + colbase + sbcol);
    __syncthreads();

    int ry = t >> 4;     // 0..15 -> rows ry*8..+7
    int tx = t & 15;     // cols tx*4..+3
    int b = 0;
    for (int k0 = kbeg; k0 < kbeg + KCH; k0 += 8, b ^= 1){
        bool more = (k0 + 8) < kbeg + KCH;
        float4 av, bv;
        if (more){
            av = *(const float4*)(inpT + (size_t)(k0 + 8 + sakk)*128 + sarow);
            if (bload)
                bv = *(const float4*)(W1 + (size_t)(k0 + 8 + sbkk)*1024 + colbase + sbcol);
        }
        #pragma unroll
        for (int kk = 0; kk < 8; ++kk){
            float af[8], bf[4];
            *(float4*)&af[0] = *(float4*)&As[b][kk][ry*8];
            *(float4*)&af[4] = *(float4*)&As[b][kk][ry*8 + 4];
            *(float4*)&bf[0] = *(float4*)&Bs[b][kk][tx*4];
            #pragma unroll
            for (int i = 0; i < 8; ++i)
                #pragma unroll
                for (int j = 0; j < 4; ++j) acc[i][j] += af[i] * bf[j];
        }
        if (more){
            *(float4*)&As[b^1][sakk][sarow] = av;
            if (bload) *(float4*)&Bs[b^1][sbkk][sbcol] = bv;
        }
        __syncthreads();
    }
    float* dst = part + (size_t)ks * 131072;
    #pragma unroll
    for (int i = 0; i < 8; ++i){
        int row = ry*8 + i;
        *(float4*)&dst[(size_t)row*1024 + colbase + tx*4] = *(float4*)&acc[i][0];
    }
}

// ---------- reduce partials + bias + sigmoid -> hidT[1024][128] ----------
__global__ void k_reduce(const float* __restrict__ part, const float* __restrict__ b1,
                         float* __restrict__ hidT)
{
    int row = blockIdx.x;                       // 0..127
    int col = blockIdx.y*256 + threadIdx.x;     // 0..1023
    float s = 0.f;
    #pragma unroll
    for (int ks = 0; ks < KSPLIT; ++ks)
        s += part[(size_t)ks*131072 + (size_t)row*1024 + col];
    hidT[(size_t)col*128 + row] = sigmoidf_(s + b1[col]);
}

// ---------- pred GEMM2: 64x64 tile, A+B staged in LDS, double-buffered ----------
// grid (313, 2); thread = 4 rows x 4 cols
__global__ __launch_bounds__(256, 4)
void k_gemm2(const float* __restrict__ hidT, const float* __restrict__ W2,
             const float* __restrict__ b2, float* __restrict__ out)
{
    int t = threadIdx.x;
    int colbase = blockIdx.x * 64;
    int rbase   = blockIdx.y * 64;
    __shared__ float As[2][8][64];
    __shared__ float Bs[2][8][64];
    float acc[4][4];
    #pragma unroll
    for (int i = 0; i < 4; ++i)
        #pragma unroll
        for (int j = 0; j < 4; ++j) acc[i][j] = 0.f;

    int u = t & 127;
    int skk = u >> 4, sc = (u & 15) * 4;
    bool aload = t < 128;
    bool bvalid = (colbase + sc) < 20000;

    if (aload)
        *(float4*)&As[0][skk][sc] =
            *(const float4*)(hidT + (size_t)skk*128 + rbase + sc);
    else {
        float4 bv = make_float4(0.f,0.f,0.f,0.f);
        if (bvalid) bv = *(const float4*)(W2 + (size_t)skk*20000 + colbase + sc);
        *(float4*)&Bs[0][skk][sc] = bv;
    }
    __syncthreads();

    int ry = t >> 4;     // 0..15 -> rows ry*4..+3
    int tx = t & 15;     // cols tx*4..+3
    int b = 0;
    for (int k0 = 0; k0 < 1024; k0 += 8, b ^= 1){
        bool more = (k0 + 8) < 1024;
        float4 v;
        if (more){
            if (aload)
                v = *(const float4*)(hidT + (size_t)(k0 + 8 + skk)*128 + rbase + sc);
            else {
                v = make_float4(0.f,0.f,0.f,0.f);
                if (bvalid) v = *(const float4*)(W2 + (size_t)(k0 + 8 + skk)*20000 + colbase + sc);
            }
        }
        #pragma unroll
        for (int kk = 0; kk < 8; ++kk){
            float af[4], bf[4];
            *(float4*)&af[0] = *(float4*)&As[b][kk][ry*4];
            *(float4*)&bf[0] = *(float4*)&Bs[b][kk][tx*4];
            #pragma unroll
            for (int i = 0; i < 4; ++i)
                #pragma unroll
                for (int j = 0; j < 4; ++j) acc[i][j] += af[i] * bf[j];
        }
        if (more){
            if (aload) *(float4*)&As[b^1][skk][sc] = v;
            else       *(float4*)&Bs[b^1][skk][sc] = v;
        }
        __syncthreads();
    }
    int col = colbase + tx*4;
    if (col < 20000){
        float4 bb = *(const float4*)(b2 + col);
        #pragma unroll
        for (int i = 0; i < 4; ++i){
            int row = rbase + ry*4 + i;
            float4 o;
            o.x = acc[i][0] + bb.x;
            o.y = acc[i][1] + bb.y;
            o.z = acc[i][2] + bb.z;
            o.w = acc[i][3] + bb.w;
            *(float4*)&out[(size_t)row*20000 + col] = o;
        }
    }
}

extern "C" void kernel_launch(void* const* d_in, const int* in_sizes, int n_in,
                              void* d_out, int out_size, void* d_ws, size_t ws_size,
                              hipStream_t stream)
{
    const float* x    = (const float*)d_in[0];
    const int*   ei   = (const int*)  d_in[1];
    const int*   pos  = (const int*)  d_in[2];
    const float* ctrl = (const float*)d_in[3];
    const float* pert = (const float*)d_in[4];
    const float* ge   = (const float*)d_in[5];
    const float* c1W  = (const float*)d_in[6];
    const float* c1as = (const float*)d_in[7];
    const float* c1ad = (const float*)d_in[8];
    const float* c1b  = (const float*)d_in[9];
    const float* l1W  = (const float*)d_in[10];
    const float* l1b  = (const float*)d_in[11];
    const float* c2W  = (const float*)d_in[12];
    const float* c2as = (const float*)d_in[13];
    const float* c2ad = (const float*)d_in[14];
    const float* c2b  = (const float*)d_in[15];
    const float* l2W  = (const float*)d_in[16];
    const float* l2b  = (const float*)d_in[17];
    const float* pW1  = (const float*)d_in[18];
    const float* pb1  = (const float*)d_in[19];
    const float* pW2  = (const float*)d_in[20];
    const float* pb2  = (const float*)d_in[21];
    const float* prW1 = (const float*)d_in[22];
    const float* prb1 = (const float*)d_in[23];
    const float* prW2 = (const float*)d_in[24];
    const float* prb2 = (const float*)d_in[25];
    float* out = (float*)d_out;

    char* ws = (char*)d_ws;
    size_t off = 0;
    auto alloc = [&](size_t bytes)->void*{
        void* pp = ws + off;
        off += (bytes + 255) & ~(size_t)255;
        return pp;
    };
    float* hc1  = (float*)alloc((size_t)G*320*4);      // 25.6 MB, dead after k_gat1
    float* h1   = (float*)alloc((size_t)G*64*4);
    float* es1  = (float*)alloc((size_t)G*4*4);
    float* ed1  = (float*)alloc((size_t)G*4*4);
    float* hh2  = (float*)alloc((size_t)G*4*4);
    float* es2  = (float*)alloc((size_t)G*4*4);
    float* ed2  = (float*)alloc((size_t)G*4*4);
    float* lv   = (float*)alloc((size_t)G*4);
    float* feat = (float*)alloc((size_t)G*4);
    float* hidT = (float*)alloc((size_t)1024*128*4);
    float* inpT = (float*)alloc((size_t)20064*128*4);  // 10.3 MB
    int*   cnt  = (int*)alloc((size_t)G*4);
    int*   offs = (int*)alloc((size_t)(G+1)*4);
    int*   cur  = (int*)alloc((size_t)G*4);
    int*   csr  = (int*)alloc((size_t)E_EDGES*4);
    float* part = hc1;   // alias: 33*128*1024*4 = 17.3 MB <= 25.6 MB, lifetimes disjoint

    hipMemsetAsync(cnt, 0, (size_t)G*4, stream);

    k_hist   <<<(E_EDGES+255)/256, 256, 0, stream>>>(ei, cnt);
    k_scan   <<<1, 1024, 0, stream>>>(cnt, offs);
    k_cursor <<<(G+255)/256, 256, 0, stream>>>(offs, cur);
    k_scatter<<<(E_EDGES+255)/256, 256, 0, stream>>>(ei, cur, csr);

    k_hc       <<<G, 320, 0, stream>>>(x, pos, ge, c1W, l1W, hc1);
    k_attn_coef<<<G, 256, 0, stream>>>(hc1, c1as, c1ad, es1, ed1);
    k_gat1     <<<G, 256, 0, stream>>>(hc1, es1, ed1, offs, csr, c1b, l1b, h1);
    k_conv2prep<<<G, 64, 0, stream>>>(h1, c2W, c2as, c2ad, l2W, hh2, es2, ed2, lv);
    k_gat2     <<<G, 64, 0, stream>>>(hh2, es2, ed2, offs, csr, lv, c2b, l2b, feat);

    dim3 gt(313, 2);
    k_transpose<<<gt, 256, 0, stream>>>(ctrl, feat, inpT);
    k_pert     <<<BATCH, 128, 0, stream>>>(pert, pW1, pb1, pW2, pb2, inpT);

    dim3 g1(16, KSPLIT);
    k_gemm1 <<<g1, 256, 0, stream>>>(inpT, prW1, part);
    dim3 gr(128, 4);
    k_reduce<<<gr, 256, 0, stream>>>(part, prb1, hidT);
    dim3 g2(313, 2);
    k_gemm2 <<<g2, 256, 0, stream>>>(hidT, prW2, prb2, out);
}

// Round 5
// 748.569 us; speedup vs baseline: 1.4679x; 1.4679x over previous
//
#include <hip/hip_runtime.h>
#include <math.h>

#define G 20000
#define E_EDGES 640000
#define HID 64
#define NHEAD 4
#define BATCH 128
#define PD 600
#define NEG 0.2f
#define MAXE 1024

#define KA1 20096          // 20064 padded to multiple of 32
#define NSTEP1 628         // 20096 / 32
#define KSPLIT1 32
#define KA2 1024

typedef float v4f __attribute__((ext_vector_type(4)));
typedef short short8 __attribute__((ext_vector_type(8)));

__device__ __forceinline__ float sigmoidf_(float x){ return 1.0f/(1.0f+__expf(-x)); }
__device__ __forceinline__ float leakyf_(float x){ return x>=0.f ? x : NEG*x; }
__device__ __forceinline__ unsigned short f2bf(float f){
    unsigned int u = __float_as_uint(f);
    return (unsigned short)((u + 0x7FFFu + ((u >> 16) & 1u)) >> 16);
}

// ---------- Stage 1: hc = [x | gene_embed[pos]] @ [conv1_W | lin1_W]  (G x 320) ----------
__global__ void k_hc(const float* __restrict__ x, const int* __restrict__ pos,
                     const float* __restrict__ ge, const float* __restrict__ Wc,
                     const float* __restrict__ Wl, float* __restrict__ hc)
{
    int i = blockIdx.x;
    int t = threadIdx.x; // 320 threads
    __shared__ float xc[65];
    if (t < 65) xc[t] = (t == 0) ? x[i] : ge[pos[i]*HID + (t-1)];
    __syncthreads();
    float acc = 0.f;
    if (t < 256) {
        for (int k = 0; k < 65; ++k) acc += xc[k] * Wc[k*256 + t];
    } else {
        int c = t - 256;
        for (int k = 0; k < 65; ++k) acc += xc[k] * Wl[k*64 + c];
    }
    hc[i*320 + t] = acc;
}

// ---------- e_src / e_dst for conv1 ----------
__global__ void k_attn_coef(const float* __restrict__ hc, const float* __restrict__ as_,
                            const float* __restrict__ ad_, float* __restrict__ es,
                            float* __restrict__ ed)
{
    int i = blockIdx.x; int t = threadIdx.x; // 256
    float hv = hc[i*320 + t];
    float v1 = hv * as_[t];
    float v2 = hv * ad_[t];
    for (int m = 32; m; m >>= 1) { v1 += __shfl_xor(v1, m); v2 += __shfl_xor(v2, m); }
    if ((t & 63) == 0) { int h = t >> 6; es[i*4+h] = v1; ed[i*4+h] = v2; }
}

// ---------- CSR build ----------
__global__ void k_hist(const int* __restrict__ ei, int* __restrict__ cnt){
    int e = blockIdx.x*blockDim.x + threadIdx.x;
    if (e < E_EDGES) atomicAdd(&cnt[ei[E_EDGES + e]], 1);
}
__global__ void k_scan(const int* __restrict__ cnt, int* __restrict__ offs){
    __shared__ int buf[1024];
    __shared__ int carry;
    int t = threadIdx.x;
    if (t == 0){ carry = 0; offs[0] = 0; }
    __syncthreads();
    for (int base = 0; base < G; base += 1024){
        int v = (base + t < G) ? cnt[base + t] : 0;
        buf[t] = v; __syncthreads();
        for (int off = 1; off < 1024; off <<= 1){
            int add = (t >= off) ? buf[t - off] : 0;
            __syncthreads();
            buf[t] += add;
            __syncthreads();
        }
        if (base + t < G) offs[base + t + 1] = carry + buf[t];
        __syncthreads();
        if (t == 0) carry += buf[1023];
        __syncthreads();
    }
}
__global__ void k_cursor(const int* __restrict__ offs, int* __restrict__ cur){
    int i = blockIdx.x*blockDim.x + threadIdx.x;
    if (i < G) cur[i] = offs[i];
}
__global__ void k_scatter(const int* __restrict__ ei, int* __restrict__ cur, int* __restrict__ csr){
    int e = blockIdx.x*blockDim.x + threadIdx.x;
    if (e < E_EDGES){
        int d = ei[E_EDGES + e];
        int p = atomicAdd(&cur[d], 1);
        csr[p] = ei[e];
    }
}

// ---------- GAT1 apply ----------
__global__ void k_gat1(const float* __restrict__ hc, const float* __restrict__ es,
                       const float* __restrict__ ed, const int* __restrict__ offs,
                       const int* __restrict__ csr, const float* __restrict__ bc1,
                       const float* __restrict__ bl1, float* __restrict__ h1)
{
    int d = blockIdx.x; int t = threadIdx.x; // 256
    __shared__ float cache[MAXE*4];
    __shared__ int   ssrc[MAXE];
    __shared__ float red[256];
    __shared__ float bc[8];
    int o = offs[d];
    int deg = offs[d+1] - o;
    int total = deg + 1;              // + self loop
    if (total > MAXE) total = MAXE;
    float edst[4];
    #pragma unroll
    for (int h = 0; h < 4; ++h) edst[h] = ed[d*4+h];
    float lmax[4] = {-1e30f,-1e30f,-1e30f,-1e30f};
    for (int idx = t; idx < total; idx += 256){
        int s = (idx < deg) ? csr[o + idx] : d;
        ssrc[idx] = s;
        #pragma unroll
        for (int h = 0; h < 4; ++h){
            float e = leakyf_(es[s*4+h] + edst[h]);
            cache[idx*4+h] = e;
            lmax[h] = fmaxf(lmax[h], e);
        }
    }
    __syncthreads();
    #pragma unroll
    for (int h = 0; h < 4; ++h){
        red[t] = lmax[h]; __syncthreads();
        for (int s2 = 128; s2; s2 >>= 1){ if (t < s2) red[t] = fmaxf(red[t], red[t+s2]); __syncthreads(); }
        if (t == 0) bc[h] = red[0];
        __syncthreads();
    }
    float m0 = bc[0], m1 = bc[1], m2 = bc[2], m3 = bc[3];
    float lsum[4] = {0.f,0.f,0.f,0.f};
    for (int idx = t; idx < total; idx += 256){
        float e0 = __expf(cache[idx*4+0] - m0); cache[idx*4+0] = e0; lsum[0] += e0;
        float e1 = __expf(cache[idx*4+1] - m1); cache[idx*4+1] = e1; lsum[1] += e1;
        float e2 = __expf(cache[idx*4+2] - m2); cache[idx*4+2] = e2; lsum[2] += e2;
        float e3 = __expf(cache[idx*4+3] - m3); cache[idx*4+3] = e3; lsum[3] += e3;
    }
    __syncthreads();
    #pragma unroll
    for (int h = 0; h < 4; ++h){
        red[t] = lsum[h]; __syncthreads();
        for (int s2 = 128; s2; s2 >>= 1){ if (t < s2) red[t] += red[t+s2]; __syncthreads(); }
        if (t == 0) bc[4+h] = 1.0f / red[0];
        __syncthreads();
    }
    int h = t >> 6, c = t & 63;
    float inv = bc[4+h];
    float acc = 0.f;
    for (int idx = 0; idx < total; ++idx){
        int s = ssrc[idx];
        float alpha = cache[idx*4+h] * inv;
        acc += alpha * hc[s*320 + h*64 + c];
    }
    red[t] = acc;
    __syncthreads();
    if (t < 64){
        float sum = red[t] + red[64+t] + red[128+t] + red[192+t];
        float val = 0.25f*sum + bc1[t] + hc[d*320 + 256 + t] + bl1[t];
        h1[d*64 + t] = sigmoidf_(val);
    }
}

// ---------- conv2 prep ----------
__global__ void k_conv2prep(const float* __restrict__ h1, const float* __restrict__ W2c,
                            const float* __restrict__ as2, const float* __restrict__ ad2,
                            const float* __restrict__ Wl2, float* __restrict__ hh2,
                            float* __restrict__ es2, float* __restrict__ ed2,
                            float* __restrict__ lv)
{
    int i = blockIdx.x; int k = threadIdx.x; // 64
    float hv = h1[i*64 + k];
    #pragma unroll
    for (int j = 0; j < 4; ++j){
        float v = hv * W2c[k*4 + j];
        for (int m = 32; m; m >>= 1) v += __shfl_xor(v, m);
        if (k == 0){ hh2[i*4+j] = v; es2[i*4+j] = v*as2[j]; ed2[i*4+j] = v*ad2[j]; }
    }
    float v = hv * Wl2[k];
    for (int m = 32; m; m >>= 1) v += __shfl_xor(v, m);
    if (k == 0) lv[i] = v;
}

// ---------- GAT2 apply ----------
__global__ void k_gat2(const float* __restrict__ hh2, const float* __restrict__ es2,
                       const float* __restrict__ ed2, const int* __restrict__ offs,
                       const int* __restrict__ csr, const float* __restrict__ lv,
                       const float* __restrict__ bc2, const float* __restrict__ bl2,
                       float* __restrict__ feat)
{
    int d = blockIdx.x; int j = threadIdx.x; // 64
    int o = offs[d];
    int deg = offs[d+1] - o;
    int total = deg + 1;
    float edst[4];
    #pragma unroll
    for (int h = 0; h < 4; ++h) edst[h] = ed2[d*4+h];
    float lmax[4] = {-1e30f,-1e30f,-1e30f,-1e30f};
    for (int idx = j; idx < total; idx += 64){
        int s = (idx < deg) ? csr[o + idx] : d;
        #pragma unroll
        for (int h = 0; h < 4; ++h)
            lmax[h] = fmaxf(lmax[h], leakyf_(es2[s*4+h] + edst[h]));
    }
    #pragma unroll
    for (int h = 0; h < 4; ++h)
        for (int m = 32; m; m >>= 1) lmax[h] = fmaxf(lmax[h], __shfl_xor(lmax[h], m));
    float lsum[4] = {0.f,0.f,0.f,0.f};
    float lnum[4] = {0.f,0.f,0.f,0.f};
    for (int idx = j; idx < total; idx += 64){
        int s = (idx < deg) ? csr[o + idx] : d;
        #pragma unroll
        for (int h = 0; h < 4; ++h){
            float e  = leakyf_(es2[s*4+h] + edst[h]);
            float ex = __expf(e - lmax[h]);
            lsum[h] += ex;
            lnum[h] += ex * hh2[s*4+h];
        }
    }
    #pragma unroll
    for (int h = 0; h < 4; ++h){
        for (int m = 32; m; m >>= 1){ lsum[h] += __shfl_xor(lsum[h], m); lnum[h] += __shfl_xor(lnum[h], m); }
    }
    if (j == 0){
        float sum = 0.f;
        #pragma unroll
        for (int h = 0; h < 4; ++h) sum += lnum[h] / lsum[h];
        feat[d] = sigmoidf_(0.25f*sum + bc2[0] + lv[d] + bl2[0]);
    }
}

// ---------- prep A1 (bf16, [row][k], row-major = ctrl's layout, no transpose) ----------
__global__ void k_prepA(const float* __restrict__ ctrl, const float* __restrict__ feat,
                        unsigned short* __restrict__ Abf)
{
    int col = blockIdx.x*256 + threadIdx.x;
    int row = blockIdx.y;
    if (col < 20000)
        Abf[(size_t)row*KA1 + col] = f2bf(ctrl[(size_t)row*20000 + col] + feat[col]);
}

// ---------- pert MLP -> writes Abf1 cols 20000..20063 (+ zero pad to 20095) ----------
__global__ void k_pert(const float* __restrict__ pert, const float* __restrict__ W1,
                       const float* __restrict__ b1, const float* __restrict__ W2,
                       const float* __restrict__ b2, unsigned short* __restrict__ Abf)
{
    int r = blockIdx.x; int t = threadIdx.x; // 128
    __shared__ float hid[128];
    float acc = 0.f;
    for (int k = 0; k < PD; ++k) acc += pert[r*PD + k] * W1[k*128 + t];
    hid[t] = sigmoidf_(acc + b1[t]);
    __syncthreads();
    if (t < 64){
        float a2 = 0.f;
        for (int k = 0; k < 128; ++k) a2 += hid[k] * W2[k*64 + t];
        Abf[(size_t)r*KA1 + 20000 + t] = f2bf(a2 + b2[t]);
    } else if (t < 96){
        Abf[(size_t)r*KA1 + 20000 + t] = 0;  // zero K-pad 20064..20095
    }
}

// ---------- pred GEMM1 (MFMA bf16): part[ks] = A[128 x Kchunk] @ W1 ----------
// grid (16 ncol, KSPLIT1); 4 waves, each: 16-col slice x 8 m-tiles of 16x16x32.
// NOTE: (256,2) not (256,4) -- the (256,4) heuristic squeezed to 64 VGPR + scratch spill (round 4).
__global__ __launch_bounds__(256, 2)
void k_gemm1m(const unsigned short* __restrict__ Abf, const float* __restrict__ W1,
              float* __restrict__ part)
{
    int t = threadIdx.x;
    int lane = t & 63, wv = t >> 6;
    int lane16 = lane & 15, quad = lane >> 4, quad8 = quad * 8;
    int colbase = blockIdx.x * 64;
    int ks = blockIdx.y;
    int sbeg = (ks * NSTEP1) / KSPLIT1;
    int send = ((ks + 1) * NSTEP1) / KSPLIT1;
    int nsteps = send - sbeg;
    int kbeg = sbeg * 32;
    __shared__ unsigned short Bs[2][32*64];

    v4f acc[8];
    #pragma unroll
    for (int i = 0; i < 8; ++i) acc[i] = (v4f){0.f,0.f,0.f,0.f};

    int krow = t >> 3;           // 0..31
    int ng   = (t & 7) * 8;      // 0..56
    // stage step 0
    {
        int kg = kbeg + krow;
        short8 p;
        if (kg < 20064){
            float4 a = *(const float4*)(W1 + (size_t)kg*1024 + colbase + ng);
            float4 b = *(const float4*)(W1 + (size_t)kg*1024 + colbase + ng + 4);
            p[0]=(short)f2bf(a.x); p[1]=(short)f2bf(a.y); p[2]=(short)f2bf(a.z); p[3]=(short)f2bf(a.w);
            p[4]=(short)f2bf(b.x); p[5]=(short)f2bf(b.y); p[6]=(short)f2bf(b.z); p[7]=(short)f2bf(b.w);
        } else {
            p = (short8){0,0,0,0,0,0,0,0};
        }
        *(short8*)&Bs[0][krow*64 + ng] = p;
    }
    __syncthreads();

    int cur = 0;
    for (int s = 0; s < nsteps; ++s){
        int kg = kbeg + s*32;
        // B fragment for this wave's 16-col slice
        short8 bfrag;
        #pragma unroll
        for (int j = 0; j < 8; ++j)
            bfrag[j] = (short)Bs[cur][(quad8 + j)*64 + wv*16 + lane16];
        // prefetch next W tile to regs
        float w[8];
        bool more = (s + 1) < nsteps;
        if (more){
            int kn = kg + 32 + krow;
            if (kn < 20064){
                float4 a = *(const float4*)(W1 + (size_t)kn*1024 + colbase + ng);
                float4 b = *(const float4*)(W1 + (size_t)kn*1024 + colbase + ng + 4);
                w[0]=a.x; w[1]=a.y; w[2]=a.z; w[3]=a.w; w[4]=b.x; w[5]=b.y; w[6]=b.z; w[7]=b.w;
            } else {
                #pragma unroll
                for (int i = 0; i < 8; ++i) w[i] = 0.f;
            }
        }
        // A fragments straight from global (L2/L3-resident) + MFMA
        #pragma unroll
        for (int mt = 0; mt < 8; ++mt){
            short8 af = *(const short8*)(Abf + (size_t)(mt*16 + lane16)*KA1 + kg + quad8);
            acc[mt] = __builtin_amdgcn_mfma_f32_16x16x32_bf16(af, bfrag, acc[mt], 0, 0, 0);
        }
        if (more){
            short8 p;
            #pragma unroll
            for (int i = 0; i < 8; ++i) p[i] = (short)f2bf(w[i]);
            *(short8*)&Bs[cur^1][krow*64 + ng] = p;
        }
        __syncthreads();
        cur ^= 1;
    }
    float* dst = part + (size_t)ks * 131072;
    int col = colbase + wv*16 + lane16;
    #pragma unroll
    for (int mt = 0; mt < 8; ++mt)
        #pragma unroll
        for (int r = 0; r < 4; ++r)
            dst[(size_t)(mt*16 + quad*4 + r)*1024 + col] = acc[mt][r];
}

// ---------- reduce partials + bias + sigmoid -> hidbf[128][1024] bf16 ----------
__global__ void k_reduce(const float* __restrict__ part, const float* __restrict__ b1,
                         unsigned short* __restrict__ hidbf)
{
    int row = blockIdx.x;                       // 0..127
    int col = blockIdx.y*256 + threadIdx.x;     // 0..1023
    float s = 0.f;
    #pragma unroll
    for (int ks = 0; ks < KSPLIT1; ++ks)
        s += part[(size_t)ks*131072 + (size_t)row*1024 + col];
    hidbf[(size_t)row*1024 + col] = f2bf(sigmoidf_(s + b1[col]));
}

// ---------- pred GEMM2 (MFMA bf16): out = hid[128x1024] @ W2 + b2 ----------
// grid (313 ncol, 2 mhalf); 4 waves x 16-col slice x 4 m-tiles.
__global__ __launch_bounds__(256, 2)
void k_gemm2m(const unsigned short* __restrict__ hidbf, const float* __restrict__ W2,
              const float* __restrict__ b2, float* __restrict__ out)
{
    int t = threadIdx.x;
    int lane = t & 63, wv = t >> 6;
    int lane16 = lane & 15, quad = lane >> 4, quad8 = quad * 8;
    int colbase = blockIdx.x * 64;
    int rbase   = blockIdx.y * 64;
    __shared__ unsigned short Bs[2][32*64];

    v4f acc[4];
    #pragma unroll
    for (int i = 0; i < 4; ++i) acc[i] = (v4f){0.f,0.f,0.f,0.f};

    int krow = t >> 3;
    int ng   = (t & 7) * 8;
    bool cv = (colbase + ng) < 20000;   // 8-col granule, 20000 % 8 == 0
    {
        short8 p = (short8){0,0,0,0,0,0,0,0};
        if (cv){
            float4 a = *(const float4*)(W2 + (size_t)krow*20000 + colbase + ng);
            float4 b = *(const float4*)(W2 + (size_t)krow*20000 + colbase + ng + 4);
            p[0]=(short)f2bf(a.x); p[1]=(short)f2bf(a.y); p[2]=(short)f2bf(a.z); p[3]=(short)f2bf(a.w);
            p[4]=(short)f2bf(b.x); p[5]=(short)f2bf(b.y); p[6]=(short)f2bf(b.z); p[7]=(short)f2bf(b.w);
        }
        *(short8*)&Bs[0][krow*64 + ng] = p;
    }
    __syncthreads();

    int cur = 0;
    for (int s = 0; s < 32; ++s){
        int kg = s*32;
        short8 bfrag;
        #pragma unroll
        for (int j = 0; j < 8; ++j)
            bfrag[j] = (short)Bs[cur][(quad8 + j)*64 + wv*16 + lane16];
        float w[8];
        bool more = s < 31;
        if (more){
            if (cv){
                int kn = kg + 32 + krow;
                float4 a = *(const float4*)(W2 + (size_t)kn*20000 + colbase + ng);
                float4 b = *(const float4*)(W2 + (size_t)kn*20000 + colbase + ng + 4);
                w[0]=a.x; w[1]=a.y; w[2]=a.z; w[3]=a.w; w[4]=b.x; w[5]=b.y; w[6]=b.z; w[7]=b.w;
            } else {
                #pragma unroll
                for (int i = 0; i < 8; ++i) w[i] = 0.f;
            }
        }
        #pragma unroll
        for (int mt = 0; mt < 4; ++mt){
            short8 af = *(const short8*)(hidbf + (size_t)(rbase + mt*16 + lane16)*KA2 + kg + quad8);
            acc[mt] = __builtin_amdgcn_mfma_f32_16x16x32_bf16(af, bfrag, acc[mt], 0, 0, 0);
        }
        if (more){
            short8 p;
            #pragma unroll
            for (int i = 0; i < 8; ++i) p[i] = (short)f2bf(w[i]);
            *(short8*)&Bs[cur^1][krow*64 + ng] = p;
        }
        __syncthreads();
        cur ^= 1;
    }
    int col = colbase + wv*16 + lane16;
    if (col < 20000){
        float bb = b2[col];
        #pragma unroll
        for (int mt = 0; mt < 4; ++mt)
            #pragma unroll
            for (int r = 0; r < 4; ++r)
                out[(size_t)(rbase + mt*16 + quad*4 + r)*20000 + col] = acc[mt][r] + bb;
    }
}

extern "C" void kernel_launch(void* const* d_in, const int* in_sizes, int n_in,
                              void* d_out, int out_size, void* d_ws, size_t ws_size,
                              hipStream_t stream)
{
    const float* x    = (const float*)d_in[0];
    const int*   ei   = (const int*)  d_in[1];
    const int*   pos  = (const int*)  d_in[2];
    const float* ctrl = (const float*)d_in[3];
    const float* pert = (const float*)d_in[4];
    const float* ge   = (const float*)d_in[5];
    const float* c1W  = (const float*)d_in[6];
    const float* c1as = (const float*)d_in[7];
    const float* c1ad = (const float*)d_in[8];
    const float* c1b  = (const float*)d_in[9];
    const float* l1W  = (const float*)d_in[10];
    const float* l1b  = (const float*)d_in[11];
    const float* c2W  = (const float*)d_in[12];
    const float* c2as = (const float*)d_in[13];
    const float* c2ad = (const float*)d_in[14];
    const float* c2b  = (const float*)d_in[15];
    const float* l2W  = (const float*)d_in[16];
    const float* l2b  = (const float*)d_in[17];
    const float* pW1  = (const float*)d_in[18];
    const float* pb1  = (const float*)d_in[19];
    const float* pW2  = (const float*)d_in[20];
    const float* pb2  = (const float*)d_in[21];
    const float* prW1 = (const float*)d_in[22];
    const float* prb1 = (const float*)d_in[23];
    const float* prW2 = (const float*)d_in[24];
    const float* prb2 = (const float*)d_in[25];
    float* out = (float*)d_out;

    char* ws = (char*)d_ws;
    size_t off = 0;
    auto alloc = [&](size_t bytes)->void*{
        void* pp = ws + off;
        off += (bytes + 255) & ~(size_t)255;
        return pp;
    };
    float* hc1  = (float*)alloc((size_t)G*320*4);      // 25.6 MB, dead after k_gat1
    float* h1   = (float*)alloc((size_t)G*64*4);
    float* es1  = (float*)alloc((size_t)G*4*4);
    float* ed1  = (float*)alloc((size_t)G*4*4);
    float* hh2  = (float*)alloc((size_t)G*4*4);
    float* es2  = (float*)alloc((size_t)G*4*4);
    float* ed2  = (float*)alloc((size_t)G*4*4);
    float* lv   = (float*)alloc((size_t)G*4);
    float* feat = (float*)alloc((size_t)G*4);
    unsigned short* hidbf = (unsigned short*)alloc((size_t)128*KA2*2);
    unsigned short* Abf1  = (unsigned short*)alloc((size_t)128*KA1*2);   // 5.1 MB
    int*   cnt  = (int*)alloc((size_t)G*4);
    int*   offs = (int*)alloc((size_t)(G+1)*4);
    int*   cur  = (int*)alloc((size_t)G*4);
    int*   csr  = (int*)alloc((size_t)E_EDGES*4);
    float* part = hc1;   // alias: 32*128*1024*4 = 16.8 MB <= 25.6 MB, lifetimes disjoint

    hipMemsetAsync(cnt, 0, (size_t)G*4, stream);

    k_hist   <<<(E_EDGES+255)/256, 256, 0, stream>>>(ei, cnt);
    k_scan   <<<1, 1024, 0, stream>>>(cnt, offs);
    k_cursor <<<(G+255)/256, 256, 0, stream>>>(offs, cur);
    k_scatter<<<(E_EDGES+255)/256, 256, 0, stream>>>(ei, cur, csr);

    k_hc       <<<G, 320, 0, stream>>>(x, pos, ge, c1W, l1W, hc1);
    k_attn_coef<<<G, 256, 0, stream>>>(hc1, c1as, c1ad, es1, ed1);
    k_gat1     <<<G, 256, 0, stream>>>(hc1, es1, ed1, offs, csr, c1b, l1b, h1);
    k_conv2prep<<<G, 64, 0, stream>>>(h1, c2W, c2as, c2ad, l2W, hh2, es2, ed2, lv);
    k_gat2     <<<G, 64, 0, stream>>>(hh2, es2, ed2, offs, csr, lv, c2b, l2b, feat);

    dim3 gp(79, 128);
    k_prepA<<<gp, 256, 0, stream>>>(ctrl, feat, Abf1);
    k_pert <<<BATCH, 128, 0, stream>>>(pert, pW1, pb1, pW2, pb2, Abf1);

    dim3 g1(16, KSPLIT1);
    k_gemm1m<<<g1, 256, 0, stream>>>(Abf1, prW1, part);
    dim3 gr(128, 4);
    k_reduce<<<gr, 256, 0, stream>>>(part, prb1, hidbf);
    dim3 g2(313, 2);
    k_gemm2m<<<g2, 256, 0, stream>>>(hidbf, prW2, prb2, out);
}

// Round 6
// 732.076 us; speedup vs baseline: 1.5010x; 1.0225x over previous
//
#include <hip/hip_runtime.h>
#include <math.h>

#define G 20000
#define E_EDGES 640000
#define HID 64
#define NHEAD 4
#define BATCH 128
#define PD 600
#define NEG 0.2f
#define MAXE 1024

#define KA1 20096          // 20064 padded to multiple of 32
#define NSTEP1 628         // 20096 / 32
#define KSPLIT1 32
#define KA2 1024

typedef float v4f __attribute__((ext_vector_type(4)));
typedef short short8 __attribute__((ext_vector_type(8)));

__device__ __forceinline__ float sigmoidf_(float x){ return 1.0f/(1.0f+__expf(-x)); }
__device__ __forceinline__ float leakyf_(float x){ return x>=0.f ? x : NEG*x; }
__device__ __forceinline__ unsigned short f2bf(float f){
    unsigned int u = __float_as_uint(f);
    return (unsigned short)((u + 0x7FFFu + ((u >> 16) & 1u)) >> 16);
}
__device__ __forceinline__ float bf2f(unsigned short b){
    return __uint_as_float(((unsigned int)b) << 16);
}

// ---------- Stage 1 fused: hc/es/ed.  64 rows/block, 320 threads.
// cols 0..255 -> hcb bf16 (gather operand) + es/ed via wave shuffle (wave==head)
// cols 256..319 -> hlin fp32 (lin1 residual)
__global__ __launch_bounds__(320)
void k_hc(const float* __restrict__ x, const int* __restrict__ pos,
          const float* __restrict__ ge, const float* __restrict__ Wc,
          const float* __restrict__ Wl, const float* __restrict__ as_,
          const float* __restrict__ ad_,
          unsigned short* __restrict__ hcb, float* __restrict__ hlin,
          float* __restrict__ es, float* __restrict__ ed)
{
    int t = threadIdx.x;                 // 320
    int rb = blockIdx.x * 64;            // grid 313
    __shared__ float xc[64][68];         // row stride 272B (16B aligned)
    for (int l = t; l < 64*65; l += 320){
        int r = l / 65, k = l - r*65;
        int row = rb + r;
        float v = 0.f;
        if (row < G) v = (k == 0) ? x[row] : ge[pos[row]*HID + (k-1)];
        xc[r][k] = v;
    }
    float wcol[65];
    if (t < 256){
        #pragma unroll
        for (int k = 0; k < 65; ++k) wcol[k] = Wc[k*256 + t];
    } else {
        int c = t - 256;
        #pragma unroll
        for (int k = 0; k < 65; ++k) wcol[k] = Wl[k*64 + c];
    }
    float a_s = 0.f, a_d = 0.f;
    if (t < 256){ a_s = as_[t]; a_d = ad_[t]; }
    __syncthreads();

    int nrow = G - rb; if (nrow > 64) nrow = 64;
    for (int r = 0; r < nrow; ++r){
        int row = rb + r;
        const float4* xr = (const float4*)&xc[r][0];
        float acc = 0.f;
        #pragma unroll
        for (int k4 = 0; k4 < 16; ++k4){
            float4 v = xr[k4];
            acc += v.x*wcol[4*k4] + v.y*wcol[4*k4+1] + v.z*wcol[4*k4+2] + v.w*wcol[4*k4+3];
        }
        acc += xc[r][64] * wcol[64];
        if (t < 256){
            hcb[(size_t)row*256 + t] = f2bf(acc);
            float v1 = acc * a_s, v2 = acc * a_d;
            #pragma unroll
            for (int m = 32; m; m >>= 1){ v1 += __shfl_xor(v1, m); v2 += __shfl_xor(v2, m); }
            if ((t & 63) == 0){ int h = t >> 6; es[row*4+h] = v1; ed[row*4+h] = v2; }
        } else {
            hlin[(size_t)row*64 + (t - 256)] = acc;
        }
    }
}

// ---------- CSR build ----------
__global__ void k_hist(const int* __restrict__ ei, int* __restrict__ cnt){
    int e = blockIdx.x*blockDim.x + threadIdx.x;
    if (e < E_EDGES) atomicAdd(&cnt[ei[E_EDGES + e]], 1);
}
// parallel scan: 20 elems/thread + one 1024-wide block scan; also writes cur
__global__ void k_scan(const int* __restrict__ cnt, int* __restrict__ offs,
                       int* __restrict__ cur)
{
    __shared__ int ts[1024];
    int t = threadIdx.x;
    int base = t * 20;
    int loc[20];
    int s = 0;
    #pragma unroll
    for (int j = 0; j < 20; ++j){
        int i = base + j;
        int v = (i < G) ? cnt[i] : 0;
        loc[j] = s; s += v;
    }
    ts[t] = s;
    __syncthreads();
    for (int off = 1; off < 1024; off <<= 1){
        int add = (t >= off) ? ts[t - off] : 0;
        __syncthreads();
        ts[t] += add;
        __syncthreads();
    }
    int tb = (t == 0) ? 0 : ts[t - 1];
    #pragma unroll
    for (int j = 0; j < 20; ++j){
        int i = base + j;
        if (i < G){ int o = tb + loc[j]; offs[i] = o; cur[i] = o; }
    }
    if (t == 0) offs[G] = ts[1023];
}
__global__ void k_scatter(const int* __restrict__ ei, int* __restrict__ cur, int* __restrict__ csr){
    int e = blockIdx.x*blockDim.x + threadIdx.x;
    if (e < E_EDGES){
        int d = ei[E_EDGES + e];
        int p = atomicAdd(&cur[d], 1);
        csr[p] = ei[e];
    }
}

// ---------- GAT1 apply: softmax + bf16 gather SpMM + head-mean + lin1 + sigmoid ----------
__global__ void k_gat1(const unsigned short* __restrict__ hcb, const float* __restrict__ hlin,
                       const float* __restrict__ es, const float* __restrict__ ed,
                       const int* __restrict__ offs, const int* __restrict__ csr,
                       const float* __restrict__ bc1, const float* __restrict__ bl1,
                       float* __restrict__ h1)
{
    int d = blockIdx.x; int t = threadIdx.x; // 256
    __shared__ float cache[MAXE*4];
    __shared__ int   ssrc[MAXE];
    __shared__ float red[256];
    __shared__ float bc[8];
    int o = offs[d];
    int deg = offs[d+1] - o;
    int total = deg + 1;              // + self loop
    if (total > MAXE) total = MAXE;
    float edst[4];
    #pragma unroll
    for (int h = 0; h < 4; ++h) edst[h] = ed[d*4+h];
    float lmax[4] = {-1e30f,-1e30f,-1e30f,-1e30f};
    for (int idx = t; idx < total; idx += 256){
        int s = (idx < deg) ? csr[o + idx] : d;
        ssrc[idx] = s;
        #pragma unroll
        for (int h = 0; h < 4; ++h){
            float e = leakyf_(es[s*4+h] + edst[h]);
            cache[idx*4+h] = e;
            lmax[h] = fmaxf(lmax[h], e);
        }
    }
    __syncthreads();
    #pragma unroll
    for (int h = 0; h < 4; ++h){
        red[t] = lmax[h]; __syncthreads();
        for (int s2 = 128; s2; s2 >>= 1){ if (t < s2) red[t] = fmaxf(red[t], red[t+s2]); __syncthreads(); }
        if (t == 0) bc[h] = red[0];
        __syncthreads();
    }
    float m0 = bc[0], m1 = bc[1], m2 = bc[2], m3 = bc[3];
    float lsum[4] = {0.f,0.f,0.f,0.f};
    for (int idx = t; idx < total; idx += 256){
        float e0 = __expf(cache[idx*4+0] - m0); cache[idx*4+0] = e0; lsum[0] += e0;
        float e1 = __expf(cache[idx*4+1] - m1); cache[idx*4+1] = e1; lsum[1] += e1;
        float e2 = __expf(cache[idx*4+2] - m2); cache[idx*4+2] = e2; lsum[2] += e2;
        float e3 = __expf(cache[idx*4+3] - m3); cache[idx*4+3] = e3; lsum[3] += e3;
    }
    __syncthreads();
    #pragma unroll
    for (int h = 0; h < 4; ++h){
        red[t] = lsum[h]; __syncthreads();
        for (int s2 = 128; s2; s2 >>= 1){ if (t < s2) red[t] += red[t+s2]; __syncthreads(); }
        if (t == 0) bc[4+h] = 1.0f / red[0];
        __syncthreads();
    }
    int h = t >> 6;
    float inv = bc[4+h];
    float acc0 = 0.f, acc1 = 0.f;
    int idx = 0;
    for (; idx + 2 <= total; idx += 2){
        int s0 = ssrc[idx], s1 = ssrc[idx+1];
        float a0 = cache[idx*4+h], a1 = cache[(idx+1)*4+h];
        float v0 = bf2f(hcb[(size_t)s0*256 + t]);
        float v1 = bf2f(hcb[(size_t)s1*256 + t]);
        acc0 += a0 * v0;
        acc1 += a1 * v1;
    }
    if (idx < total){
        int s0 = ssrc[idx];
        acc0 += cache[idx*4+h] * bf2f(hcb[(size_t)s0*256 + t]);
    }
    red[t] = (acc0 + acc1) * inv;
    __syncthreads();
    if (t < 64){
        float sum = red[t] + red[64+t] + red[128+t] + red[192+t];
        float val = 0.25f*sum + bc1[t] + hlin[(size_t)d*64 + t] + bl1[t];
        h1[d*64 + t] = sigmoidf_(val);
    }
}

// ---------- conv2 prep ----------
__global__ void k_conv2prep(const float* __restrict__ h1, const float* __restrict__ W2c,
                            const float* __restrict__ as2, const float* __restrict__ ad2,
                            const float* __restrict__ Wl2, float* __restrict__ hh2,
                            float* __restrict__ es2, float* __restrict__ ed2,
                            float* __restrict__ lv)
{
    int i = blockIdx.x; int k = threadIdx.x; // 64
    float hv = h1[i*64 + k];
    #pragma unroll
    for (int j = 0; j < 4; ++j){
        float v = hv * W2c[k*4 + j];
        for (int m = 32; m; m >>= 1) v += __shfl_xor(v, m);
        if (k == 0){ hh2[i*4+j] = v; es2[i*4+j] = v*as2[j]; ed2[i*4+j] = v*ad2[j]; }
    }
    float v = hv * Wl2[k];
    for (int m = 32; m; m >>= 1) v += __shfl_xor(v, m);
    if (k == 0) lv[i] = v;
}

// ---------- GAT2 apply ----------
__global__ void k_gat2(const float* __restrict__ hh2, const float* __restrict__ es2,
                       const float* __restrict__ ed2, const int* __restrict__ offs,
                       const int* __restrict__ csr, const float* __restrict__ lv,
                       const float* __restrict__ bc2, const float* __restrict__ bl2,
                       float* __restrict__ feat)
{
    int d = blockIdx.x; int j = threadIdx.x; // 64
    int o = offs[d];
    int deg = offs[d+1] - o;
    int total = deg + 1;
    float edst[4];
    #pragma unroll
    for (int h = 0; h < 4; ++h) edst[h] = ed2[d*4+h];
    float lmax[4] = {-1e30f,-1e30f,-1e30f,-1e30f};
    for (int idx = j; idx < total; idx += 64){
        int s = (idx < deg) ? csr[o + idx] : d;
        #pragma unroll
        for (int h = 0; h < 4; ++h)
            lmax[h] = fmaxf(lmax[h], leakyf_(es2[s*4+h] + edst[h]));
    }
    #pragma unroll
    for (int h = 0; h < 4; ++h)
        for (int m = 32; m; m >>= 1) lmax[h] = fmaxf(lmax[h], __shfl_xor(lmax[h], m));
    float lsum[4] = {0.f,0.f,0.f,0.f};
    float lnum[4] = {0.f,0.f,0.f,0.f};
    for (int idx = j; idx < total; idx += 64){
        int s = (idx < deg) ? csr[o + idx] : d;
        #pragma unroll
        for (int h = 0; h < 4; ++h){
            float e  = leakyf_(es2[s*4+h] + edst[h]);
            float ex = __expf(e - lmax[h]);
            lsum[h] += ex;
            lnum[h] += ex * hh2[s*4+h];
        }
    }
    #pragma unroll
    for (int h = 0; h < 4; ++h){
        for (int m = 32; m; m >>= 1){ lsum[h] += __shfl_xor(lsum[h], m); lnum[h] += __shfl_xor(lnum[h], m); }
    }
    if (j == 0){
        float sum = 0.f;
        #pragma unroll
        for (int h = 0; h < 4; ++h) sum += lnum[h] / lsum[h];
        feat[d] = sigmoidf_(0.25f*sum + bc2[0] + lv[d] + bl2[0]);
    }
}

// ---------- prep A1 (bf16, [row][k], row-major = ctrl's layout, no transpose) ----------
__global__ void k_prepA(const float* __restrict__ ctrl, const float* __restrict__ feat,
                        unsigned short* __restrict__ Abf)
{
    int col = blockIdx.x*256 + threadIdx.x;
    int row = blockIdx.y;
    if (col < 20000)
        Abf[(size_t)row*KA1 + col] = f2bf(ctrl[(size_t)row*20000 + col] + feat[col]);
}

// ---------- pert MLP -> writes Abf1 cols 20000..20063 (+ zero pad to 20095) ----------
__global__ void k_pert(const float* __restrict__ pert, const float* __restrict__ W1,
                       const float* __restrict__ b1, const float* __restrict__ W2,
                       const float* __restrict__ b2, unsigned short* __restrict__ Abf)
{
    int r = blockIdx.x; int t = threadIdx.x; // 128
    __shared__ float hid[128];
    float acc = 0.f;
    for (int k = 0; k < PD; ++k) acc += pert[r*PD + k] * W1[k*128 + t];
    hid[t] = sigmoidf_(acc + b1[t]);
    __syncthreads();
    if (t < 64){
        float a2 = 0.f;
        for (int k = 0; k < 128; ++k) a2 += hid[k] * W2[k*64 + t];
        Abf[(size_t)r*KA1 + 20000 + t] = f2bf(a2 + b2[t]);
    } else if (t < 96){
        Abf[(size_t)r*KA1 + 20000 + t] = 0;  // zero K-pad 20064..20095
    }
}

// ---------- pred GEMM1 (MFMA bf16): part[ks] = A[128 x Kchunk] @ W1 ----------
__global__ __launch_bounds__(256, 2)
void k_gemm1m(const unsigned short* __restrict__ Abf, const float* __restrict__ W1,
              float* __restrict__ part)
{
    int t = threadIdx.x;
    int lane = t & 63, wv = t >> 6;
    int lane16 = lane & 15, quad = lane >> 4, quad8 = quad * 8;
    int colbase = blockIdx.x * 64;
    int ks = blockIdx.y;
    int sbeg = (ks * NSTEP1) / KSPLIT1;
    int send = ((ks + 1) * NSTEP1) / KSPLIT1;
    int nsteps = send - sbeg;
    int kbeg = sbeg * 32;
    __shared__ unsigned short Bs[2][32*64];

    v4f acc[8];
    #pragma unroll
    for (int i = 0; i < 8; ++i) acc[i] = (v4f){0.f,0.f,0.f,0.f};

    int krow = t >> 3;           // 0..31
    int ng   = (t & 7) * 8;      // 0..56
    {
        int kg = kbeg + krow;
        short8 p;
        if (kg < 20064){
            float4 a = *(const float4*)(W1 + (size_t)kg*1024 + colbase + ng);
            float4 b = *(const float4*)(W1 + (size_t)kg*1024 + colbase + ng + 4);
            p[0]=(short)f2bf(a.x); p[1]=(short)f2bf(a.y); p[2]=(short)f2bf(a.z); p[3]=(short)f2bf(a.w);
            p[4]=(short)f2bf(b.x); p[5]=(short)f2bf(b.y); p[6]=(short)f2bf(b.z); p[7]=(short)f2bf(b.w);
        } else {
            p = (short8){0,0,0,0,0,0,0,0};
        }
        *(short8*)&Bs[0][krow*64 + ng] = p;
    }
    __syncthreads();

    int cur = 0;
    for (int s = 0; s < nsteps; ++s){
        int kg = kbeg + s*32;
        short8 bfrag;
        #pragma unroll
        for (int j = 0; j < 8; ++j)
            bfrag[j] = (short)Bs[cur][(quad8 + j)*64 + wv*16 + lane16];
        float w[8];
        bool more = (s + 1) < nsteps;
        if (more){
            int kn = kg + 32 + krow;
            if (kn < 20064){
                float4 a = *(const float4*)(W1 + (size_t)kn*1024 + colbase + ng);
                float4 b = *(const float4*)(W1 + (size_t)kn*1024 + colbase + ng + 4);
                w[0]=a.x; w[1]=a.y; w[2]=a.z; w[3]=a.w; w[4]=b.x; w[5]=b.y; w[6]=b.z; w[7]=b.w;
            } else {
                #pragma unroll
                for (int i = 0; i < 8; ++i) w[i] = 0.f;
            }
        }
        #pragma unroll
        for (int mt = 0; mt < 8; ++mt){
            short8 af = *(const short8*)(Abf + (size_t)(mt*16 + lane16)*KA1 + kg + quad8);
            acc[mt] = __builtin_amdgcn_mfma_f32_16x16x32_bf16(af, bfrag, acc[mt], 0, 0, 0);
        }
        if (more){
            short8 p;
            #pragma unroll
            for (int i = 0; i < 8; ++i) p[i] = (short)f2bf(w[i]);
            *(short8*)&Bs[cur^1][krow*64 + ng] = p;
        }
        __syncthreads();
        cur ^= 1;
    }
    float* dst = part + (size_t)ks * 131072;
    int col = colbase + wv*16 + lane16;
    #pragma unroll
    for (int mt = 0; mt < 8; ++mt)
        #pragma unroll
        for (int r = 0; r < 4; ++r)
            dst[(size_t)(mt*16 + quad*4 + r)*1024 + col] = acc[mt][r];
}

// ---------- reduce partials + bias + sigmoid -> hidbf[128][1024] bf16 ----------
__global__ void k_reduce(const float* __restrict__ part, const float* __restrict__ b1,
                         unsigned short* __restrict__ hidbf)
{
    int row = blockIdx.x;                       // 0..127
    int col = blockIdx.y*256 + threadIdx.x;     // 0..1023
    float s = 0.f;
    #pragma unroll
    for (int ks = 0; ks < KSPLIT1; ++ks)
        s += part[(size_t)ks*131072 + (size_t)row*1024 + col];
    hidbf[(size_t)row*1024 + col] = f2bf(sigmoidf_(s + b1[col]));
}

// ---------- pred GEMM2 (MFMA bf16): out = hid[128x1024] @ W2 + b2 ----------
__global__ __launch_bounds__(256, 2)
void k_gemm2m(const unsigned short* __restrict__ hidbf, const float* __restrict__ W2,
              const float* __restrict__ b2, float* __restrict__ out)
{
    int t = threadIdx.x;
    int lane = t & 63, wv = t >> 6;
    int lane16 = lane & 15, quad = lane >> 4, quad8 = quad * 8;
    int colbase = blockIdx.x * 64;
    int rbase   = blockIdx.y * 64;
    __shared__ unsigned short Bs[2][32*64];

    v4f acc[4];
    #pragma unroll
    for (int i = 0; i < 4; ++i) acc[i] = (v4f){0.f,0.f,0.f,0.f};

    int krow = t >> 3;
    int ng   = (t & 7) * 8;
    bool cv = (colbase + ng) < 20000;   // 8-col granule, 20000 % 8 == 0
    {
        short8 p = (short8){0,0,0,0,0,0,0,0};
        if (cv){
            float4 a = *(const float4*)(W2 + (size_t)krow*20000 + colbase + ng);
            float4 b = *(const float4*)(W2 + (size_t)krow*20000 + colbase + ng + 4);
            p[0]=(short)f2bf(a.x); p[1]=(short)f2bf(a.y); p[2]=(short)f2bf(a.z); p[3]=(short)f2bf(a.w);
            p[4]=(short)f2bf(b.x); p[5]=(short)f2bf(b.y); p[6]=(short)f2bf(b.z); p[7]=(short)f2bf(b.w);
        }
        *(short8*)&Bs[0][krow*64 + ng] = p;
    }
    __syncthreads();

    int cur = 0;
    for (int s = 0; s < 32; ++s){
        int kg = s*32;
        short8 bfrag;
        #pragma unroll
        for (int j = 0; j < 8; ++j)
            bfrag[j] = (short)Bs[cur][(quad8 + j)*64 + wv*16 + lane16];
        float w[8];
        bool more = s < 31;
        if (more){
            if (cv){
                int kn = kg + 32 + krow;
                float4 a = *(const float4*)(W2 + (size_t)kn*20000 + colbase + ng);
                float4 b = *(const float4*)(W2 + (size_t)kn*20000 + colbase + ng + 4);
                w[0]=a.x; w[1]=a.y; w[2]=a.z; w[3]=a.w; w[4]=b.x; w[5]=b.y; w[6]=b.z; w[7]=b.w;
            } else {
                #pragma unroll
                for (int i = 0; i < 8; ++i) w[i] = 0.f;
            }
        }
        #pragma unroll
        for (int mt = 0; mt < 4; ++mt){
            short8 af = *(const short8*)(hidbf + (size_t)(rbase + mt*16 + lane16)*KA2 + kg + quad8);
            acc[mt] = __builtin_amdgcn_mfma_f32_16x16x32_bf16(af, bfrag, acc[mt], 0, 0, 0);
        }
        if (more){
            short8 p;
            #pragma unroll
            for (int i = 0; i < 8; ++i) p[i] = (short)f2bf(w[i]);
            *(short8*)&Bs[cur^1][krow*64 + ng] = p;
        }
        __syncthreads();
        cur ^= 1;
    }
    int col = colbase + wv*16 + lane16;
    if (col < 20000){
        float bb = b2[col];
        #pragma unroll
        for (int mt = 0; mt < 4; ++mt)
            #pragma unroll
            for (int r = 0; r < 4; ++r)
                out[(size_t)(rbase + mt*16 + quad*4 + r)*20000 + col] = acc[mt][r] + bb;
    }
}

extern "C" void kernel_launch(void* const* d_in, const int* in_sizes, int n_in,
                              void* d_out, int out_size, void* d_ws, size_t ws_size,
                              hipStream_t stream)
{
    const float* x    = (const float*)d_in[0];
    const int*   ei   = (const int*)  d_in[1];
    const int*   pos  = (const int*)  d_in[2];
    const float* ctrl = (const float*)d_in[3];
    const float* pert = (const float*)d_in[4];
    const float* ge   = (const float*)d_in[5];
    const float* c1W  = (const float*)d_in[6];
    const float* c1as = (const float*)d_in[7];
    const float* c1ad = (const float*)d_in[8];
    const float* c1b  = (const float*)d_in[9];
    const float* l1W  = (const float*)d_in[10];
    const float* l1b  = (const float*)d_in[11];
    const float* c2W  = (const float*)d_in[12];
    const float* c2as = (const float*)d_in[13];
    const float* c2ad = (const float*)d_in[14];
    const float* c2b  = (const float*)d_in[15];
    const float* l2W  = (const float*)d_in[16];
    const float* l2b  = (const float*)d_in[17];
    const float* pW1  = (const float*)d_in[18];
    const float* pb1  = (const float*)d_in[19];
    const float* pW2  = (const float*)d_in[20];
    const float* pb2  = (const float*)d_in[21];
    const float* prW1 = (const float*)d_in[22];
    const float* prb1 = (const float*)d_in[23];
    const float* prW2 = (const float*)d_in[24];
    const float* prb2 = (const float*)d_in[25];
    float* out = (float*)d_out;

    char* ws = (char*)d_ws;
    size_t off = 0;
    auto alloc = [&](size_t bytes)->void*{
        void* pp = ws + off;
        off += (bytes + 255) & ~(size_t)255;
        return pp;
    };
    unsigned short* hcb  = (unsigned short*)alloc((size_t)G*256*2);  // 10.24 MB
    float* hlin = (float*)alloc((size_t)G*64*4);                      // 5.12 MB
    float* h1   = (float*)alloc((size_t)G*64*4);
    float* es1  = (float*)alloc((size_t)G*4*4);
    float* ed1  = (float*)alloc((size_t)G*4*4);
    float* hh2  = (float*)alloc((size_t)G*4*4);
    float* es2  = (float*)alloc((size_t)G*4*4);
    float* ed2  = (float*)alloc((size_t)G*4*4);
    float* lv   = (float*)alloc((size_t)G*4);
    float* feat = (float*)alloc((size_t)G*4);
    unsigned short* hidbf = (unsigned short*)alloc((size_t)128*KA2*2);
    unsigned short* Abf1  = (unsigned short*)alloc((size_t)128*KA1*2);   // 5.1 MB
    float* part = (float*)alloc((size_t)KSPLIT1*131072*4);               // 16.8 MB
    int*   cnt  = (int*)alloc((size_t)G*4);
    int*   offs = (int*)alloc((size_t)(G+1)*4);
    int*   cur  = (int*)alloc((size_t)G*4);
    int*   csr  = (int*)alloc((size_t)E_EDGES*4);

    hipMemsetAsync(cnt, 0, (size_t)G*4, stream);

    k_hist   <<<(E_EDGES+255)/256, 256, 0, stream>>>(ei, cnt);
    k_scan   <<<1, 1024, 0, stream>>>(cnt, offs, cur);
    k_scatter<<<(E_EDGES+255)/256, 256, 0, stream>>>(ei, cur, csr);

    k_hc       <<<313, 320, 0, stream>>>(x, pos, ge, c1W, l1W, c1as, c1ad,
                                         hcb, hlin, es1, ed1);
    k_gat1     <<<G, 256, 0, stream>>>(hcb, hlin, es1, ed1, offs, csr, c1b, l1b, h1);
    k_conv2prep<<<G, 64, 0, stream>>>(h1, c2W, c2as, c2ad, l2W, hh2, es2, ed2, lv);
    k_gat2     <<<G, 64, 0, stream>>>(hh2, es2, ed2, offs, csr, lv, c2b, l2b, feat);

    dim3 gp(79, 128);
    k_prepA<<<gp, 256, 0, stream>>>(ctrl, feat, Abf1);
    k_pert <<<BATCH, 128, 0, stream>>>(pert, pW1, pb1, pW2, pb2, Abf1);

    dim3 g1(16, KSPLIT1);
    k_gemm1m<<<g1, 256, 0, stream>>>(Abf1, prW1, part);
    dim3 gr(128, 4);
    k_reduce<<<gr, 256, 0, stream>>>(part, prb1, hidbf);
    dim3 g2(313, 2);
    k_gemm2m<<<g2, 256, 0, stream>>>(hidbf, prW2, prb2, out);
}